// Round 15
// baseline (78.897 us; speedup 1.0000x reference)
//
#include <hip/hip_runtime.h>

// SpectralDivergence: fft2(512x512) power spectrum -> radial profile (50 bins)
// -> per-batch KL divergence between softmaxed profiles of x and reference.
// 96 images (48 x + 48 ref), B=16, C=3, H=W=512. Output: 16 floats.
//
// R15: ROWS OCCUPANCY. R14's slo table fixed cols (top-5 is now all rows:
// occ 32%, 36.9KB LDS -> 4 blocks/CU, FETCH 49MB @ 950GB/s). Same cure as
// cols: ONE row-pair per wave, LDS 36.9 -> 16.5KB (4x float2[516] padded
// buffers; pad=516 gives +8 bank skew per wave so the cross-wave readout is
// conflict-free), stage buffer eliminated (separation -> registers -> own z
// reused as uint2[256] -> single __syncthreads -> 32B transposed writes).
// 8 blocks/CU. Arithmetic identical => absmax stays exactly 512.

#define NIMG 96
#define NB 50
#define NCOL 257
#define PHYS(k) ((k) ^ (((k) >> 3) & 7))

typedef unsigned int uint32;
typedef unsigned short ushort16;

__device__ __forceinline__ float2 cadd(float2 a, float2 b){ return make_float2(a.x+b.x, a.y+b.y); }
__device__ __forceinline__ float2 csub(float2 a, float2 b){ return make_float2(a.x-b.x, a.y-b.y); }
__device__ __forceinline__ float2 cmul(float2 a, float2 b){
  return make_float2(fmaf(a.x, b.x, -(a.y*b.y)), fmaf(a.x, b.y, a.y*b.x));
}
__device__ __forceinline__ float2 mul_mi(float2 a){ return make_float2(a.y, -a.x); }  // * -i

// pack complex -> bf16x2 (re high, im low), RNE
__device__ __forceinline__ uint32 bfpack(float re, float im) {
  uint32 ur = __float_as_uint(re); ur += 0x7FFFu + ((ur >> 16) & 1u);
  uint32 ui = __float_as_uint(im); ui += 0x7FFFu + ((ui >> 16) & 1u);
  return (ur & 0xFFFF0000u) | (ui >> 16);
}
__device__ __forceinline__ float2 bfunpack(uint32 u) {
  return make_float2(__uint_as_float(u & 0xFFFF0000u), __uint_as_float(u << 16));
}

// 8 complex values in named registers.
struct C8 { float2 m0, m1, m2, m3, m4, m5, m6, m7; };

// 8-point DFT, natural order (by value).
__device__ __forceinline__ C8 fft8(C8 v) {
  const float C = 0.70710678118654752f;
  float2 t0=cadd(v.m0,v.m4), t1=csub(v.m0,v.m4);
  float2 t2=cadd(v.m2,v.m6), t3m=mul_mi(csub(v.m2,v.m6));
  float2 E0=cadd(t0,t2), E1=cadd(t1,t3m), E2=csub(t0,t2), E3=csub(t1,t3m);
  float2 s0=cadd(v.m1,v.m5), s1=csub(v.m1,v.m5);
  float2 s2=cadd(v.m3,v.m7), s3m=mul_mi(csub(v.m3,v.m7));
  float2 O0=cadd(s0,s2), O1=cadd(s1,s3m), O2=csub(s0,s2), O3=csub(s1,s3m);
  O1 = make_float2(C*(O1.x+O1.y), C*(O1.y-O1.x));      // * W8^1
  O2 = mul_mi(O2);                                      // * W8^2
  O3 = make_float2(C*(O3.y-O3.x), -C*(O3.x+O3.y));      // * W8^3
  C8 r;
  r.m0=cadd(E0,O0); r.m4=csub(E0,O0);
  r.m1=cadd(E1,O1); r.m5=csub(E1,O1);
  r.m2=cadd(E2,O2); r.m6=csub(E2,O2);
  r.m3=cadd(E3,O3); r.m7=csub(E3,O3);
  return r;
}

#define TWAP1(X, W) do { float2 t_ = (W);                               \
  X.m1=cmul(X.m1,t_); t_=cmul(t_,(W));                                  \
  X.m2=cmul(X.m2,t_); t_=cmul(t_,(W));                                  \
  X.m3=cmul(X.m3,t_); t_=cmul(t_,(W));                                  \
  X.m4=cmul(X.m4,t_); t_=cmul(t_,(W));                                  \
  X.m5=cmul(X.m5,t_); t_=cmul(t_,(W));                                  \
  X.m6=cmul(X.m6,t_); t_=cmul(t_,(W));                                  \
  X.m7=cmul(X.m7,t_); } while(0)

// Single wave-local 512-pt FFT. Input: x.mA = data[64a + lane]; output:
// x.mq = X[(lane>>3) + 8*(lane&7) + 64q]. XOR-swizzled exchanges,
// conflict-free; wave-synchronous.
#define FFT512_1(X, Z, W1, W2, HI, LO) do {                                   \
  X = fft8(X);                                                                \
  TWAP1(X, W1);                                                               \
  Z[      8*((HI)^0)+(LO)] = X.m0;                                            \
  Z[ 64 + 8*((HI)^1)+(LO)] = X.m1;                                            \
  Z[128 + 8*((HI)^2)+(LO)] = X.m2;                                            \
  Z[192 + 8*((HI)^3)+(LO)] = X.m3;                                            \
  Z[256 + 8*((HI)^4)+(LO)] = X.m4;                                            \
  Z[320 + 8*((HI)^5)+(LO)] = X.m5;                                            \
  Z[384 + 8*((HI)^6)+(LO)] = X.m6;                                            \
  Z[448 + 8*((HI)^7)+(LO)] = X.m7;                                            \
  __builtin_amdgcn_wave_barrier();                                            \
  X.m0 = Z[64*(HI)+8*(0^(HI))+(LO)];                                          \
  X.m1 = Z[64*(HI)+8*(1^(HI))+(LO)];                                          \
  X.m2 = Z[64*(HI)+8*(2^(HI))+(LO)];                                          \
  X.m3 = Z[64*(HI)+8*(3^(HI))+(LO)];                                          \
  X.m4 = Z[64*(HI)+8*(4^(HI))+(LO)];                                          \
  X.m5 = Z[64*(HI)+8*(5^(HI))+(LO)];                                          \
  X.m6 = Z[64*(HI)+8*(6^(HI))+(LO)];                                          \
  X.m7 = Z[64*(HI)+8*(7^(HI))+(LO)];                                          \
  __builtin_amdgcn_wave_barrier();                                            \
  X = fft8(X);                                                                \
  TWAP1(X, W2);                                                               \
  Z[64*(HI)+8*(0^(HI))+((LO)^0)] = X.m0;                                      \
  Z[64*(HI)+8*(1^(HI))+((LO)^1)] = X.m1;                                      \
  Z[64*(HI)+8*(2^(HI))+((LO)^2)] = X.m2;                                      \
  Z[64*(HI)+8*(3^(HI))+((LO)^3)] = X.m3;                                      \
  Z[64*(HI)+8*(4^(HI))+((LO)^4)] = X.m4;                                      \
  Z[64*(HI)+8*(5^(HI))+((LO)^5)] = X.m5;                                      \
  Z[64*(HI)+8*(6^(HI))+((LO)^6)] = X.m6;                                      \
  Z[64*(HI)+8*(7^(HI))+((LO)^7)] = X.m7;                                      \
  __builtin_amdgcn_wave_barrier();                                            \
  X.m0 = Z[64*(HI)+8*((LO)^(HI))+(0^(LO))];                                   \
  X.m1 = Z[64*(HI)+8*((LO)^(HI))+(1^(LO))];                                   \
  X.m2 = Z[64*(HI)+8*((LO)^(HI))+(2^(LO))];                                   \
  X.m3 = Z[64*(HI)+8*((LO)^(HI))+(3^(LO))];                                   \
  X.m4 = Z[64*(HI)+8*((LO)^(HI))+(4^(LO))];                                   \
  X.m5 = Z[64*(HI)+8*((LO)^(HI))+(5^(LO))];                                   \
  X.m6 = Z[64*(HI)+8*((LO)^(HI))+(6^(LO))];                                   \
  X.m7 = Z[64*(HI)+8*((LO)^(HI))+(7^(LO))];                                   \
  __builtin_amdgcn_wave_barrier();                                            \
  X = fft8(X);                                                                \
} while(0)

#define TWIDDLE_W(W1, W2, lane)                                             \
  float2 W1, W2;                                                            \
  {                                                                         \
    float sv, cv;                                                           \
    __sincosf(-6.283185307179586f * (float)(lane) / 512.f, &sv, &cv);       \
    W1 = make_float2(cv, sv);                                               \
    __sincosf(-6.283185307179586f * (float)((lane) & 7) / 64.f, &sv, &cv);  \
    W2 = make_float2(cv, sv);                                               \
  }

// bin of a pixel at |sy|=s in column c
__device__ __forceinline__ int binOf(int s, int cc) {
  return (int)(sqrtf((float)(s * s + cc * cc)) * 0.1953125f);
}
// smallest s in [0,257] with binOf(s,cc) >= b
__device__ __forceinline__ int slo(int b, int cc) {
  if (b <= 0) return 0;
  float t = 26.2144f * (float)(b * b) - (float)(cc * cc);
  int s = (t <= 0.f) ? 0 : (int)ceilf(sqrtf(t));
  if (s > 257) s = 257;
  while (s > 0 && binOf(s - 1, cc) >= b) --s;
  while (s < 257 && binOf(s, cc) < b) ++s;
  return s;
}

// ---------------------------------------------------------------------------
// One-shot: slo table, u16 tab[c*52 + b] for c in [0,257), b in [0,51].
// ---------------------------------------------------------------------------
__global__ __launch_bounds__(256) void build_slo_table(ushort16* __restrict__ tab)
{
  const int idx = blockIdx.x * 256 + threadIdx.x;
  if (idx >= NCOL * 51) return;
  const int c = idx / 51, b = idx - c * 51;
  tab[c * 52 + b] = (ushort16)slo(b, c);
}

// ---------------------------------------------------------------------------
// Row pass: 2-for-1 packed real row FFTs, ONE pair per wave, 4 waves/block,
// 64 blocks/image. LDS 16.5KB -> 8 blocks/CU. Separation -> registers ->
// own z reused as uint2[256] -> one __syncthreads -> 32B transposed writes.
// interT is written ONLY here. Padded [516] buffers: +8 bank skew per wave
// makes the cross-wave readout conflict-free.
// ---------------------------------------------------------------------------
__global__ __launch_bounds__(256, 8) void fft_rows_T(
    const float* __restrict__ xin, const float* __restrict__ rin,
    uint32* __restrict__ outT, int img0)
{
  __shared__ float2 s_z[4][516];    // 16.5 KB
  const int tid = threadIdx.x, w = tid >> 6, lane = tid & 63;
  const int hi = lane >> 3, lo = lane & 7;
  const int imgL = blockIdx.x >> 6, blkin = blockIdx.x & 63;
  const int img = img0 + imgL;
  const float* base = (img < 48) ? (xin + (size_t)img * 262144)
                                 : (rin + (size_t)(img - 48) * 262144);
  const int rp = blkin * 4 + w;                 // rows 2rp, 2rp+1
  const float* src = base + (size_t)rp * 1024;

  TWIDDLE_W(w1, w2, lane)
  float2* z = s_z[w];
  uint32* outImg = outT + (size_t)imgL * ((size_t)NCOL * 512);

  C8 x;   // packed: row 2rp -> re, row 2rp+1 -> im
  x.m0 = make_float2(src[      lane], src[512 +       lane]);
  x.m1 = make_float2(src[ 64 + lane], src[512 +  64 + lane]);
  x.m2 = make_float2(src[128 + lane], src[512 + 128 + lane]);
  x.m3 = make_float2(src[192 + lane], src[512 + 192 + lane]);
  x.m4 = make_float2(src[256 + lane], src[512 + 256 + lane]);
  x.m5 = make_float2(src[320 + lane], src[512 + 320 + lane]);
  x.m6 = make_float2(src[384 + lane], src[512 + 384 + lane]);
  x.m7 = make_float2(src[448 + lane], src[512 + 448 + lane]);

  FFT512_1(x, z, w1, w2, hi, lo);

  // natural-order store, PHYS-swizzled (conflict-free per quarter-wave)
  z[PHYS(hi + 8*lo +   0)] = x.m0;
  z[PHYS(hi + 8*lo +  64)] = x.m1;
  z[PHYS(hi + 8*lo + 128)] = x.m2;
  z[PHYS(hi + 8*lo + 192)] = x.m3;
  z[PHYS(hi + 8*lo + 256)] = x.m4;
  z[PHYS(hi + 8*lo + 320)] = x.m5;
  z[PHYS(hi + 8*lo + 384)] = x.m6;
  z[PHYS(hi + 8*lo + 448)] = x.m7;
  __builtin_amdgcn_wave_barrier();

  // conjugate-symmetry separation -> named registers (rule #20)
#define SEPK(A, ST)                                                          \
  uint2 ST;                                                                  \
  {                                                                          \
    const int k  = 64 * (A) + lane;                                          \
    const int pk = (512 - k) & 511;                                          \
    float2 zk = z[PHYS(k)], zp = z[PHYS(pk)];                                \
    ST = make_uint2(bfpack(0.5f*(zk.x + zp.x), 0.5f*(zk.y - zp.y)),          \
                    bfpack(0.5f*(zk.y + zp.y), 0.5f*(zp.x - zk.x)));         \
  }
  SEPK(0, st0)
  SEPK(1, st1)
  SEPK(2, st2)
  SEPK(3, st3)
#undef SEPK
  float2 zn = z[256];   // freq 256 (PHYS(256)==256); slot not overwritten below
  __builtin_amdgcn_wave_barrier();

  // overwrite own z (bytes 0..2047) as uint2[256] keyed by freq k
  uint2* zU = (uint2*)z;
  zU[       lane] = st0;
  zU[ 64 +  lane] = st1;
  zU[128 +  lane] = st2;
  zU[192 +  lane] = st3;
  __syncthreads();

  // cross-wave transposed write: thread (kk,jj) writes wave jj's pair at
  // freq 64a+kk. Banks: jj*516*2 ≡ +8 skew -> 16 distinct banks per quarter.
  const int kk = tid >> 2, jj = tid & 3;
  const uint2* zUj = (const uint2*)(s_z[jj]);
  #pragma unroll
  for (int a = 0; a < 4; ++a) {
    uint2 v = zUj[64 * a + kk];
    *reinterpret_cast<uint2*>(outImg + ((size_t)(64 * a + kk) * 512
                                        + 8 * blkin + 2 * jj)) = v;
  }
  if (lane == 0) {   // freq 256 (self-paired): A=Re(Z), B=Im(Z)
    *reinterpret_cast<uint2*>(outImg + ((size_t)256 * 512 + 2 * rp)) =
        make_uint2(bfpack(zn.x, 0.f), bfpack(zn.y, 0.f));
  }
}

// ---------------------------------------------------------------------------
// Fused col pass, ONE column per wave, slo from table. 17KB LDS,
// launch_bounds(256,8) -> 8 blocks/CU. Block = 4 waves; 65 blocks/image.
// ---------------------------------------------------------------------------
__global__ __launch_bounds__(256, 8) void fft_cols_bin1(
    const uint32* __restrict__ inT, const ushort16* __restrict__ tab,
    float* __restrict__ profSum, int img0)
{
  __shared__ float2 s_z[4][512];    // 16 KB (FFT exchange, then fp32 power)
  __shared__ float s_bins[4][64];   // 1 KB
  const int tid = threadIdx.x, w = tid >> 6, lane = tid & 63;
  const int hi = lane >> 3, lo = lane & 7;
  const int imgL = blockIdx.x / 65, blkin = blockIdx.x - imgL * 65;
  const int imgG = img0 + imgL;
  const int c  = blkin * 4 + w;
  const int cs = (c <= 256) ? c : 256;
  const float wf = (c > 256) ? 0.f : ((c == 0 || c == 256) ? 1.f : 2.f);

  TWIDDLE_W(w1, w2, lane)
  float2* z = s_z[w];
  const uint32* src = inT + ((size_t)(imgL * NCOL + cs)) * 512;
  C8 x;
  x.m0 = bfunpack(src[      lane]);
  x.m1 = bfunpack(src[ 64 + lane]);
  x.m2 = bfunpack(src[128 + lane]);
  x.m3 = bfunpack(src[192 + lane]);
  x.m4 = bfunpack(src[256 + lane]);
  x.m5 = bfunpack(src[320 + lane]);
  x.m6 = bfunpack(src[384 + lane]);
  x.m7 = bfunpack(src[448 + lane]);

  // issue table loads early (L2-hot, independent of FFT)
  int ts0 = 0, ts1 = 0;
  if (lane < NB) {
    ts0 = tab[cs * 52 + lane];
    ts1 = tab[cs * 52 + lane + 1];
  }

  FFT512_1(x, z, w1, w2, hi, lo);

  // power -> LDS in natural k order (reuse z as float[512]; wave-private)
  float* zf = (float*)z;
  const int low6 = hi + 8 * lo;
  zf[low6      ] = x.m0.x*x.m0.x + x.m0.y*x.m0.y;
  zf[low6 +  64] = x.m1.x*x.m1.x + x.m1.y*x.m1.y;
  zf[low6 + 128] = x.m2.x*x.m2.x + x.m2.y*x.m2.y;
  zf[low6 + 192] = x.m3.x*x.m3.x + x.m3.y*x.m3.y;
  zf[low6 + 256] = x.m4.x*x.m4.x + x.m4.y*x.m4.y;
  zf[low6 + 320] = x.m5.x*x.m5.x + x.m5.y*x.m5.y;
  zf[low6 + 384] = x.m6.x*x.m6.x + x.m6.y*x.m6.y;
  zf[low6 + 448] = x.m7.x*x.m7.x + x.m7.y*x.m7.y;
  __builtin_amdgcn_wave_barrier();

  // contiguous 8 per lane (2x b128)
  float4 a0 = *reinterpret_cast<float4*>(&zf[8 * lane]);
  float4 a1 = *reinterpret_cast<float4*>(&zf[8 * lane + 4]);

  // local inclusive prefix over 8
  a0.y += a0.x; a0.z += a0.y; a0.w += a0.z;
  a1.x += a0.w; a1.y += a1.x; a1.z += a1.y; a1.w += a1.z;
  float tot = a1.w;

  // wave inclusive scan of lane totals
  float s = tot;
  #pragma unroll
  for (int d = 1; d < 64; d <<= 1) {
    float t = __shfl_up(s, d);
    if (lane >= d) s += t;
  }
  float off = s - tot;
  a0.x += off; a0.y += off; a0.z += off; a0.w += off;
  a1.x += off; a1.y += off; a1.z += off; a1.w += off;

  *reinterpret_cast<float4*>(&zf[8 * lane])     = a0;
  *reinterpret_cast<float4*>(&zf[8 * lane + 4]) = a1;
  __builtin_amdgcn_wave_barrier();

  // bin extraction: bin b = two prefix differences (boundaries from table)
  float acc = 0.f;
  if (lane < NB) {
    const int s0 = ts0, s1 = ts1;
    int hp = (s1 < 257 ? s1 : 257) - 1;
    float pos = ((hp >= 0) ? zf[hp] : 0.f) - ((s0 > 0) ? zf[s0 - 1] : 0.f);
    int sa = (s0 > 1) ? s0 : 1;
    int sb = (s1 - 1 < 255) ? (s1 - 1) : 255;
    float neg = (sb >= sa) ? (zf[512 - sa] - zf[511 - sb]) : 0.f;
    acc = wf * (pos + neg);
  }
  s_bins[w][lane] = acc;
  __syncthreads();
  if (tid < NB) {
    float ss = s_bins[0][tid] + s_bins[1][tid] + s_bins[2][tid] + s_bins[3][tid];
    atomicAdd(&profSum[(size_t)imgG * NB + tid], ss);
  }
}

// ---------------------------------------------------------------------------
// Radial bin counts (geometry only).
// ---------------------------------------------------------------------------
__global__ __launch_bounds__(256) void compute_counts(float* __restrict__ cnt)
{
  const int t = threadIdx.x;
  __shared__ float lb[NB];
  if (t < NB) lb[t] = 0.f;
  __syncthreads();
  const int base = blockIdx.x * 2048;
  #pragma unroll
  for (int k = 0; k < 8; ++k) {
    const int idx = base + k * 256 + t;
    const int y  = idx >> 9;
    const int xx = idx & 511;
    const int sy = (y < 256) ? y : y - 512;
    const int sx = (xx < 256) ? xx : xx - 512;
    float r = sqrtf((float)(sy * sy + sx * sx));
    int bb = (int)(r * 0.1953125f);
    if (bb < NB) atomicAdd(&lb[bb], 1.f);
  }
  __syncthreads();
  if (t < NB) atomicAdd(&cnt[t], lb[t]);
}

// ---------------------------------------------------------------------------
// Finalize: profile means -> log_softmax -> KL.
// ---------------------------------------------------------------------------
__global__ __launch_bounds__(256) void finalize_kl(
    const float* __restrict__ profSum, const float* __restrict__ cntg,
    float* __restrict__ out)
{
  const int b = blockIdx.x;
  const int t = threadIdx.x;
  __shared__ float red[256];

  float lxv = -3.0e38f, lrv = -3.0e38f;
  if (t < 150) {
    const int cc  = t / NB;
    const int bin = t - cc * NB;
    const float c = cntg[bin];
    lxv = profSum[(size_t)(b * 3 + cc) * NB + bin] / c;
    lrv = profSum[(size_t)(48 + b * 3 + cc) * NB + bin] / c;
  }
  auto rmax = [&](float v) {
    red[t] = v; __syncthreads();
    for (int s2 = 128; s2 >= 1; s2 >>= 1) {
      if (t < s2) red[t] = fmaxf(red[t], red[t + s2]);
      __syncthreads();
    }
    float rr = red[0]; __syncthreads();
    return rr;
  };
  auto rsum = [&](float v) {
    red[t] = v; __syncthreads();
    for (int s2 = 128; s2 >= 1; s2 >>= 1) {
      if (t < s2) red[t] = red[t] + red[t + s2];
      __syncthreads();
    }
    float rr = red[0]; __syncthreads();
    return rr;
  };
  const float mx  = rmax(lxv);
  const float mr  = rmax(lrv);
  const float sx  = rsum((t < 150) ? expf(lxv - mx) : 0.f);
  const float sr  = rsum((t < 150) ? expf(lrv - mr) : 0.f);
  const float lsx = logf(sx);
  const float lsr = logf(sr);
  float term = 0.f;
  if (t < 150) {
    const float logp = lxv - mx - lsx;
    const float logq = lrv - mr - lsr;
    const float q    = expf(logq);
    term = q * (logq - logp);
  }
  const float div = rsum(term);
  if (t == 0) out[b] = div;
}

// ---------------------------------------------------------------------------
extern "C" void kernel_launch(void* const* d_in, const int* in_sizes, int n_in,
                              void* d_out, int out_size, void* d_ws, size_t ws_size,
                              hipStream_t stream)
{
  const float* x = (const float*)d_in[0];
  const float* r = (const float*)d_in[1];
  float* out     = (float*)d_out;

  // ws: [0,19200) profSum; [19200,19400) counts; [19456, 19456+26728) slo
  // table (u16[257][52]); [46592, ...) interT chunks (bf16x2, 514KB/img).
  float* profSum = (float*)d_ws;
  float* cnt     = (float*)((char*)d_ws + 19200);
  ushort16* tab  = (ushort16*)((char*)d_ws + 19456);
  const size_t IM_OFS = 46592;
  uint32* interT = (uint32*)((char*)d_ws + IM_OFS);

  const size_t perImg = (size_t)NCOL * 512 * sizeof(uint32);  // ~514 KiB
  size_t avail = (ws_size > IM_OFS) ? (ws_size - IM_OFS) : 0;
  int ic = (int)(avail / perImg);
  if (ic > NIMG) ic = NIMG;
  if (ic < 1) ic = 1;

  hipMemsetAsync(d_ws, 0, 19456, stream);
  hipLaunchKernelGGL(build_slo_table, dim3(52), dim3(256), 0, stream, tab);
  hipLaunchKernelGGL(compute_counts, dim3(128), dim3(256), 0, stream, cnt);

  for (int img0 = 0; img0 < NIMG; img0 += ic) {
    const int n = (NIMG - img0 < ic) ? (NIMG - img0) : ic;
    hipLaunchKernelGGL(fft_rows_T, dim3(n * 64), dim3(256), 0, stream,
                       x, r, interT, img0);
    hipLaunchKernelGGL(fft_cols_bin1, dim3(n * 65), dim3(256), 0, stream,
                       interT, tab, profSum, img0);
  }
  hipLaunchKernelGGL(finalize_kl, dim3(16), dim3(256), 0, stream,
                     profSum, cnt, out);
}

// Round 16
// 69.147 us; speedup vs baseline: 1.1410x; 1.1410x over previous
//
#include <hip/hip_runtime.h>

// SpectralDivergence: fft2(512x512) power spectrum -> radial profile (50 bins)
// -> per-batch KL divergence between softmaxed profiles of x and reference.
// 96 images (48 x + 48 ref), B=16, C=3, H=W=512. Output: 16 floats.
//
// R16: rows = 512-thread blocks, 8 waves x ONE row-pair each, 32 blocks/img.
// Combines R14's 64B transposed-write chunks (16 rows/block) with R15's
// register-separation + 516-padded per-wave buffers (no stage buffer, one
// __syncthreads). LDS 33KB -> 4 blocks/CU x 8 waves = 100% theoretical occ
// (R14 was 32%). R15's regression was the 32B write chunks (4 pairs/block),
// not occupancy - this restores 64B while keeping the occupancy win.
// Cols/table/finalize byte-identical to R14 (69.4us best).

#define NIMG 96
#define NB 50
#define NCOL 257
#define PHYS(k) ((k) ^ (((k) >> 3) & 7))

typedef unsigned int uint32;
typedef unsigned short ushort16;

__device__ __forceinline__ float2 cadd(float2 a, float2 b){ return make_float2(a.x+b.x, a.y+b.y); }
__device__ __forceinline__ float2 csub(float2 a, float2 b){ return make_float2(a.x-b.x, a.y-b.y); }
__device__ __forceinline__ float2 cmul(float2 a, float2 b){
  return make_float2(fmaf(a.x, b.x, -(a.y*b.y)), fmaf(a.x, b.y, a.y*b.x));
}
__device__ __forceinline__ float2 mul_mi(float2 a){ return make_float2(a.y, -a.x); }  // * -i

// pack complex -> bf16x2 (re high, im low), RNE
__device__ __forceinline__ uint32 bfpack(float re, float im) {
  uint32 ur = __float_as_uint(re); ur += 0x7FFFu + ((ur >> 16) & 1u);
  uint32 ui = __float_as_uint(im); ui += 0x7FFFu + ((ui >> 16) & 1u);
  return (ur & 0xFFFF0000u) | (ui >> 16);
}
__device__ __forceinline__ float2 bfunpack(uint32 u) {
  return make_float2(__uint_as_float(u & 0xFFFF0000u), __uint_as_float(u << 16));
}

// 8 complex values in named registers.
struct C8 { float2 m0, m1, m2, m3, m4, m5, m6, m7; };

// 8-point DFT, natural order (by value).
__device__ __forceinline__ C8 fft8(C8 v) {
  const float C = 0.70710678118654752f;
  float2 t0=cadd(v.m0,v.m4), t1=csub(v.m0,v.m4);
  float2 t2=cadd(v.m2,v.m6), t3m=mul_mi(csub(v.m2,v.m6));
  float2 E0=cadd(t0,t2), E1=cadd(t1,t3m), E2=csub(t0,t2), E3=csub(t1,t3m);
  float2 s0=cadd(v.m1,v.m5), s1=csub(v.m1,v.m5);
  float2 s2=cadd(v.m3,v.m7), s3m=mul_mi(csub(v.m3,v.m7));
  float2 O0=cadd(s0,s2), O1=cadd(s1,s3m), O2=csub(s0,s2), O3=csub(s1,s3m);
  O1 = make_float2(C*(O1.x+O1.y), C*(O1.y-O1.x));      // * W8^1
  O2 = mul_mi(O2);                                      // * W8^2
  O3 = make_float2(C*(O3.y-O3.x), -C*(O3.x+O3.y));      // * W8^3
  C8 r;
  r.m0=cadd(E0,O0); r.m4=csub(E0,O0);
  r.m1=cadd(E1,O1); r.m5=csub(E1,O1);
  r.m2=cadd(E2,O2); r.m6=csub(E2,O2);
  r.m3=cadd(E3,O3); r.m7=csub(E3,O3);
  return r;
}

#define TWAP1(X, W) do { float2 t_ = (W);                               \
  X.m1=cmul(X.m1,t_); t_=cmul(t_,(W));                                  \
  X.m2=cmul(X.m2,t_); t_=cmul(t_,(W));                                  \
  X.m3=cmul(X.m3,t_); t_=cmul(t_,(W));                                  \
  X.m4=cmul(X.m4,t_); t_=cmul(t_,(W));                                  \
  X.m5=cmul(X.m5,t_); t_=cmul(t_,(W));                                  \
  X.m6=cmul(X.m6,t_); t_=cmul(t_,(W));                                  \
  X.m7=cmul(X.m7,t_); } while(0)

// Single wave-local 512-pt FFT. Input: x.mA = data[64a + lane]; output:
// x.mq = X[(lane>>3) + 8*(lane&7) + 64q]. XOR-swizzled exchanges,
// conflict-free; wave-synchronous.
#define FFT512_1(X, Z, W1, W2, HI, LO) do {                                   \
  X = fft8(X);                                                                \
  TWAP1(X, W1);                                                               \
  Z[      8*((HI)^0)+(LO)] = X.m0;                                            \
  Z[ 64 + 8*((HI)^1)+(LO)] = X.m1;                                            \
  Z[128 + 8*((HI)^2)+(LO)] = X.m2;                                            \
  Z[192 + 8*((HI)^3)+(LO)] = X.m3;                                            \
  Z[256 + 8*((HI)^4)+(LO)] = X.m4;                                            \
  Z[320 + 8*((HI)^5)+(LO)] = X.m5;                                            \
  Z[384 + 8*((HI)^6)+(LO)] = X.m6;                                            \
  Z[448 + 8*((HI)^7)+(LO)] = X.m7;                                            \
  __builtin_amdgcn_wave_barrier();                                            \
  X.m0 = Z[64*(HI)+8*(0^(HI))+(LO)];                                          \
  X.m1 = Z[64*(HI)+8*(1^(HI))+(LO)];                                          \
  X.m2 = Z[64*(HI)+8*(2^(HI))+(LO)];                                          \
  X.m3 = Z[64*(HI)+8*(3^(HI))+(LO)];                                          \
  X.m4 = Z[64*(HI)+8*(4^(HI))+(LO)];                                          \
  X.m5 = Z[64*(HI)+8*(5^(HI))+(LO)];                                          \
  X.m6 = Z[64*(HI)+8*(6^(HI))+(LO)];                                          \
  X.m7 = Z[64*(HI)+8*(7^(HI))+(LO)];                                          \
  __builtin_amdgcn_wave_barrier();                                            \
  X = fft8(X);                                                                \
  TWAP1(X, W2);                                                               \
  Z[64*(HI)+8*(0^(HI))+((LO)^0)] = X.m0;                                      \
  Z[64*(HI)+8*(1^(HI))+((LO)^1)] = X.m1;                                      \
  Z[64*(HI)+8*(2^(HI))+((LO)^2)] = X.m2;                                      \
  Z[64*(HI)+8*(3^(HI))+((LO)^3)] = X.m3;                                      \
  Z[64*(HI)+8*(4^(HI))+((LO)^4)] = X.m4;                                      \
  Z[64*(HI)+8*(5^(HI))+((LO)^5)] = X.m5;                                      \
  Z[64*(HI)+8*(6^(HI))+((LO)^6)] = X.m6;                                      \
  Z[64*(HI)+8*(7^(HI))+((LO)^7)] = X.m7;                                      \
  __builtin_amdgcn_wave_barrier();                                            \
  X.m0 = Z[64*(HI)+8*((LO)^(HI))+(0^(LO))];                                   \
  X.m1 = Z[64*(HI)+8*((LO)^(HI))+(1^(LO))];                                   \
  X.m2 = Z[64*(HI)+8*((LO)^(HI))+(2^(LO))];                                   \
  X.m3 = Z[64*(HI)+8*((LO)^(HI))+(3^(LO))];                                   \
  X.m4 = Z[64*(HI)+8*((LO)^(HI))+(4^(LO))];                                   \
  X.m5 = Z[64*(HI)+8*((LO)^(HI))+(5^(LO))];                                   \
  X.m6 = Z[64*(HI)+8*((LO)^(HI))+(6^(LO))];                                   \
  X.m7 = Z[64*(HI)+8*((LO)^(HI))+(7^(LO))];                                   \
  __builtin_amdgcn_wave_barrier();                                            \
  X = fft8(X);                                                                \
} while(0)

#define TWIDDLE_W(W1, W2, lane)                                             \
  float2 W1, W2;                                                            \
  {                                                                         \
    float sv, cv;                                                           \
    __sincosf(-6.283185307179586f * (float)(lane) / 512.f, &sv, &cv);       \
    W1 = make_float2(cv, sv);                                               \
    __sincosf(-6.283185307179586f * (float)((lane) & 7) / 64.f, &sv, &cv);  \
    W2 = make_float2(cv, sv);                                               \
  }

// bin of a pixel at |sy|=s in column c
__device__ __forceinline__ int binOf(int s, int cc) {
  return (int)(sqrtf((float)(s * s + cc * cc)) * 0.1953125f);
}
// smallest s in [0,257] with binOf(s,cc) >= b
__device__ __forceinline__ int slo(int b, int cc) {
  if (b <= 0) return 0;
  float t = 26.2144f * (float)(b * b) - (float)(cc * cc);
  int s = (t <= 0.f) ? 0 : (int)ceilf(sqrtf(t));
  if (s > 257) s = 257;
  while (s > 0 && binOf(s - 1, cc) >= b) --s;
  while (s < 257 && binOf(s, cc) < b) ++s;
  return s;
}

// ---------------------------------------------------------------------------
// One-shot: slo table, u16 tab[c*52 + b] for c in [0,257), b in [0,51].
// ---------------------------------------------------------------------------
__global__ __launch_bounds__(256) void build_slo_table(ushort16* __restrict__ tab)
{
  const int idx = blockIdx.x * 256 + threadIdx.x;
  if (idx >= NCOL * 51) return;
  const int c = idx / 51, b = idx - c * 51;
  tab[c * 52 + b] = (ushort16)slo(b, c);
}

// ---------------------------------------------------------------------------
// Row pass: 2-for-1 packed real row FFTs, 512 threads = 8 waves x 1 pair,
// 32 blocks/image. LDS 33KB (8x float2[516] padded) -> 4 blocks/CU = 100%
// theoretical occupancy. Separation in registers; own z reused as
// uint2[256]; one __syncthreads; 64B-chunk transposed writes (16 rows/blk).
// interT written ONLY here.
// ---------------------------------------------------------------------------
__global__ __launch_bounds__(512, 8) void fft_rows_T(
    const float* __restrict__ xin, const float* __restrict__ rin,
    uint32* __restrict__ outT, int img0)
{
  __shared__ float2 s_z[8][516];    // 33 KB
  const int tid = threadIdx.x, w = tid >> 6, lane = tid & 63;
  const int hi = lane >> 3, lo = lane & 7;
  const int imgL = blockIdx.x >> 5, blkin = blockIdx.x & 31;
  const int img = img0 + imgL;
  const float* base = (img < 48) ? (xin + (size_t)img * 262144)
                                 : (rin + (size_t)(img - 48) * 262144);
  const int rp = blkin * 8 + w;                 // rows 2rp, 2rp+1
  const float* src = base + (size_t)rp * 1024;

  TWIDDLE_W(w1, w2, lane)
  float2* z = s_z[w];
  uint32* outImg = outT + (size_t)imgL * ((size_t)NCOL * 512);

  C8 x;   // packed: row 2rp -> re, row 2rp+1 -> im
  x.m0 = make_float2(src[      lane], src[512 +       lane]);
  x.m1 = make_float2(src[ 64 + lane], src[512 +  64 + lane]);
  x.m2 = make_float2(src[128 + lane], src[512 + 128 + lane]);
  x.m3 = make_float2(src[192 + lane], src[512 + 192 + lane]);
  x.m4 = make_float2(src[256 + lane], src[512 + 256 + lane]);
  x.m5 = make_float2(src[320 + lane], src[512 + 320 + lane]);
  x.m6 = make_float2(src[384 + lane], src[512 + 384 + lane]);
  x.m7 = make_float2(src[448 + lane], src[512 + 448 + lane]);

  FFT512_1(x, z, w1, w2, hi, lo);

  // natural-order store, PHYS-swizzled (conflict-free per quarter-wave)
  z[PHYS(hi + 8*lo +   0)] = x.m0;
  z[PHYS(hi + 8*lo +  64)] = x.m1;
  z[PHYS(hi + 8*lo + 128)] = x.m2;
  z[PHYS(hi + 8*lo + 192)] = x.m3;
  z[PHYS(hi + 8*lo + 256)] = x.m4;
  z[PHYS(hi + 8*lo + 320)] = x.m5;
  z[PHYS(hi + 8*lo + 384)] = x.m6;
  z[PHYS(hi + 8*lo + 448)] = x.m7;
  __builtin_amdgcn_wave_barrier();

  // conjugate-symmetry separation -> named registers (rule #20)
#define SEPK(A, ST)                                                          \
  uint2 ST;                                                                  \
  {                                                                          \
    const int k  = 64 * (A) + lane;                                          \
    const int pk = (512 - k) & 511;                                          \
    float2 zk = z[PHYS(k)], zp = z[PHYS(pk)];                                \
    ST = make_uint2(bfpack(0.5f*(zk.x + zp.x), 0.5f*(zk.y - zp.y)),          \
                    bfpack(0.5f*(zk.y + zp.y), 0.5f*(zp.x - zk.x)));         \
  }
  SEPK(0, st0)
  SEPK(1, st1)
  SEPK(2, st2)
  SEPK(3, st3)
#undef SEPK
  float2 zn = z[256];   // freq 256 (PHYS(256)==256); slot not overwritten below
  __builtin_amdgcn_wave_barrier();

  // overwrite own z (bytes 0..2047) as uint2[256] keyed by freq k
  uint2* zU = (uint2*)z;
  zU[       lane] = st0;
  zU[ 64 +  lane] = st1;
  zU[128 +  lane] = st2;
  zU[192 +  lane] = st3;
  __syncthreads();

  // cross-wave transposed write: thread (kk,jj) writes wave jj's pair at
  // freq 64a+kk. 8 waves -> 16B*4... 8 x uint2 = 64B contiguous per freq.
  // Banks: jj stride = 516*2 dwords ≡ +8, kk stride +2 -> ≤2-way (free).
  const int kk = tid >> 3, jj = tid & 7;        // kk: 0..63, jj: 0..7
  const uint2* zUj = (const uint2*)(s_z[jj]);
  #pragma unroll
  for (int a = 0; a < 4; ++a) {
    uint2 v = zUj[64 * a + kk];
    *reinterpret_cast<uint2*>(outImg + ((size_t)(64 * a + kk) * 512
                                        + 16 * blkin + 2 * jj)) = v;
  }
  if (lane == 0) {   // freq 256 (self-paired): A=Re(Z), B=Im(Z)
    *reinterpret_cast<uint2*>(outImg + ((size_t)256 * 512 + 2 * rp)) =
        make_uint2(bfpack(zn.x, 0.f), bfpack(zn.y, 0.f));
  }
}

// ---------------------------------------------------------------------------
// Fused col pass, ONE column per wave, slo from table. 17KB LDS,
// launch_bounds(256,8) -> 8 blocks/CU. Block = 4 waves; 65 blocks/image.
// (Byte-identical to R14.)
// ---------------------------------------------------------------------------
__global__ __launch_bounds__(256, 8) void fft_cols_bin1(
    const uint32* __restrict__ inT, const ushort16* __restrict__ tab,
    float* __restrict__ profSum, int img0)
{
  __shared__ float2 s_z[4][512];    // 16 KB (FFT exchange, then fp32 power)
  __shared__ float s_bins[4][64];   // 1 KB
  const int tid = threadIdx.x, w = tid >> 6, lane = tid & 63;
  const int hi = lane >> 3, lo = lane & 7;
  const int imgL = blockIdx.x / 65, blkin = blockIdx.x - imgL * 65;
  const int imgG = img0 + imgL;
  const int c  = blkin * 4 + w;
  const int cs = (c <= 256) ? c : 256;
  const float wf = (c > 256) ? 0.f : ((c == 0 || c == 256) ? 1.f : 2.f);

  TWIDDLE_W(w1, w2, lane)
  float2* z = s_z[w];
  const uint32* src = inT + ((size_t)(imgL * NCOL + cs)) * 512;
  C8 x;
  x.m0 = bfunpack(src[      lane]);
  x.m1 = bfunpack(src[ 64 + lane]);
  x.m2 = bfunpack(src[128 + lane]);
  x.m3 = bfunpack(src[192 + lane]);
  x.m4 = bfunpack(src[256 + lane]);
  x.m5 = bfunpack(src[320 + lane]);
  x.m6 = bfunpack(src[384 + lane]);
  x.m7 = bfunpack(src[448 + lane]);

  // issue table loads early (L2-hot, independent of FFT)
  int ts0 = 0, ts1 = 0;
  if (lane < NB) {
    ts0 = tab[cs * 52 + lane];
    ts1 = tab[cs * 52 + lane + 1];
  }

  FFT512_1(x, z, w1, w2, hi, lo);

  // power -> LDS in natural k order (reuse z as float[512]; wave-private)
  float* zf = (float*)z;
  const int low6 = hi + 8 * lo;
  zf[low6      ] = x.m0.x*x.m0.x + x.m0.y*x.m0.y;
  zf[low6 +  64] = x.m1.x*x.m1.x + x.m1.y*x.m1.y;
  zf[low6 + 128] = x.m2.x*x.m2.x + x.m2.y*x.m2.y;
  zf[low6 + 192] = x.m3.x*x.m3.x + x.m3.y*x.m3.y;
  zf[low6 + 256] = x.m4.x*x.m4.x + x.m4.y*x.m4.y;
  zf[low6 + 320] = x.m5.x*x.m5.x + x.m5.y*x.m5.y;
  zf[low6 + 384] = x.m6.x*x.m6.x + x.m6.y*x.m6.y;
  zf[low6 + 448] = x.m7.x*x.m7.x + x.m7.y*x.m7.y;
  __builtin_amdgcn_wave_barrier();

  // contiguous 8 per lane (2x b128)
  float4 a0 = *reinterpret_cast<float4*>(&zf[8 * lane]);
  float4 a1 = *reinterpret_cast<float4*>(&zf[8 * lane + 4]);

  // local inclusive prefix over 8
  a0.y += a0.x; a0.z += a0.y; a0.w += a0.z;
  a1.x += a0.w; a1.y += a1.x; a1.z += a1.y; a1.w += a1.z;
  float tot = a1.w;

  // wave inclusive scan of lane totals
  float s = tot;
  #pragma unroll
  for (int d = 1; d < 64; d <<= 1) {
    float t = __shfl_up(s, d);
    if (lane >= d) s += t;
  }
  float off = s - tot;
  a0.x += off; a0.y += off; a0.z += off; a0.w += off;
  a1.x += off; a1.y += off; a1.z += off; a1.w += off;

  *reinterpret_cast<float4*>(&zf[8 * lane])     = a0;
  *reinterpret_cast<float4*>(&zf[8 * lane + 4]) = a1;
  __builtin_amdgcn_wave_barrier();

  // bin extraction: bin b = two prefix differences (boundaries from table)
  float acc = 0.f;
  if (lane < NB) {
    const int s0 = ts0, s1 = ts1;
    int hp = (s1 < 257 ? s1 : 257) - 1;
    float pos = ((hp >= 0) ? zf[hp] : 0.f) - ((s0 > 0) ? zf[s0 - 1] : 0.f);
    int sa = (s0 > 1) ? s0 : 1;
    int sb = (s1 - 1 < 255) ? (s1 - 1) : 255;
    float neg = (sb >= sa) ? (zf[512 - sa] - zf[511 - sb]) : 0.f;
    acc = wf * (pos + neg);
  }
  s_bins[w][lane] = acc;
  __syncthreads();
  if (tid < NB) {
    float ss = s_bins[0][tid] + s_bins[1][tid] + s_bins[2][tid] + s_bins[3][tid];
    atomicAdd(&profSum[(size_t)imgG * NB + tid], ss);
  }
}

// ---------------------------------------------------------------------------
// Radial bin counts (geometry only).
// ---------------------------------------------------------------------------
__global__ __launch_bounds__(256) void compute_counts(float* __restrict__ cnt)
{
  const int t = threadIdx.x;
  __shared__ float lb[NB];
  if (t < NB) lb[t] = 0.f;
  __syncthreads();
  const int base = blockIdx.x * 2048;
  #pragma unroll
  for (int k = 0; k < 8; ++k) {
    const int idx = base + k * 256 + t;
    const int y  = idx >> 9;
    const int xx = idx & 511;
    const int sy = (y < 256) ? y : y - 512;
    const int sx = (xx < 256) ? xx : xx - 512;
    float r = sqrtf((float)(sy * sy + sx * sx));
    int bb = (int)(r * 0.1953125f);
    if (bb < NB) atomicAdd(&lb[bb], 1.f);
  }
  __syncthreads();
  if (t < NB) atomicAdd(&cnt[t], lb[t]);
}

// ---------------------------------------------------------------------------
// Finalize: profile means -> log_softmax -> KL.
// ---------------------------------------------------------------------------
__global__ __launch_bounds__(256) void finalize_kl(
    const float* __restrict__ profSum, const float* __restrict__ cntg,
    float* __restrict__ out)
{
  const int b = blockIdx.x;
  const int t = threadIdx.x;
  __shared__ float red[256];

  float lxv = -3.0e38f, lrv = -3.0e38f;
  if (t < 150) {
    const int cc  = t / NB;
    const int bin = t - cc * NB;
    const float c = cntg[bin];
    lxv = profSum[(size_t)(b * 3 + cc) * NB + bin] / c;
    lrv = profSum[(size_t)(48 + b * 3 + cc) * NB + bin] / c;
  }
  auto rmax = [&](float v) {
    red[t] = v; __syncthreads();
    for (int s2 = 128; s2 >= 1; s2 >>= 1) {
      if (t < s2) red[t] = fmaxf(red[t], red[t + s2]);
      __syncthreads();
    }
    float rr = red[0]; __syncthreads();
    return rr;
  };
  auto rsum = [&](float v) {
    red[t] = v; __syncthreads();
    for (int s2 = 128; s2 >= 1; s2 >>= 1) {
      if (t < s2) red[t] = red[t] + red[t + s2];
      __syncthreads();
    }
    float rr = red[0]; __syncthreads();
    return rr;
  };
  const float mx  = rmax(lxv);
  const float mr  = rmax(lrv);
  const float sx  = rsum((t < 150) ? expf(lxv - mx) : 0.f);
  const float sr  = rsum((t < 150) ? expf(lrv - mr) : 0.f);
  const float lsx = logf(sx);
  const float lsr = logf(sr);
  float term = 0.f;
  if (t < 150) {
    const float logp = lxv - mx - lsx;
    const float logq = lrv - mr - lsr;
    const float q    = expf(logq);
    term = q * (logq - logp);
  }
  const float div = rsum(term);
  if (t == 0) out[b] = div;
}

// ---------------------------------------------------------------------------
extern "C" void kernel_launch(void* const* d_in, const int* in_sizes, int n_in,
                              void* d_out, int out_size, void* d_ws, size_t ws_size,
                              hipStream_t stream)
{
  const float* x = (const float*)d_in[0];
  const float* r = (const float*)d_in[1];
  float* out     = (float*)d_out;

  // ws: [0,19200) profSum; [19200,19400) counts; [19456, 19456+26728) slo
  // table (u16[257][52]); [46592, ...) interT chunks (bf16x2, 514KB/img).
  float* profSum = (float*)d_ws;
  float* cnt     = (float*)((char*)d_ws + 19200);
  ushort16* tab  = (ushort16*)((char*)d_ws + 19456);
  const size_t IM_OFS = 46592;
  uint32* interT = (uint32*)((char*)d_ws + IM_OFS);

  const size_t perImg = (size_t)NCOL * 512 * sizeof(uint32);  // ~514 KiB
  size_t avail = (ws_size > IM_OFS) ? (ws_size - IM_OFS) : 0;
  int ic = (int)(avail / perImg);
  if (ic > NIMG) ic = NIMG;
  if (ic < 1) ic = 1;

  hipMemsetAsync(d_ws, 0, 19456, stream);
  hipLaunchKernelGGL(build_slo_table, dim3(52), dim3(256), 0, stream, tab);
  hipLaunchKernelGGL(compute_counts, dim3(128), dim3(256), 0, stream, cnt);

  for (int img0 = 0; img0 < NIMG; img0 += ic) {
    const int n = (NIMG - img0 < ic) ? (NIMG - img0) : ic;
    hipLaunchKernelGGL(fft_rows_T, dim3(n * 32), dim3(512), 0, stream,
                       x, r, interT, img0);
    hipLaunchKernelGGL(fft_cols_bin1, dim3(n * 65), dim3(256), 0, stream,
                       interT, tab, profSum, img0);
  }
  hipLaunchKernelGGL(finalize_kl, dim3(16), dim3(256), 0, stream,
                     profSum, cnt, out);
}